// Round 6
// baseline (186.501 us; speedup 1.0000x reference)
//
#include <hip/hip_runtime.h>
#include <hip/hip_bf16.h>

// CZ gate: out[i] = state[i], sign flipped iff bits c2,t2 of the flat index
// are both set (D = 2^n, so flat-index bits == column-index bits).
// Pure 1 GiB R+W streaming op; roofline = float4-copy ceiling ~6.3 TB/s.
//
// History: r2 plain NT loop = 197 us; r3 4x unroll at 8MB-separated
// addresses REGRESSED (247 us, DRAM locality); r4 2x block-contiguous = 190;
// r5 4x block-contiguous = 179.5 us (5.98 TB/s, 95% of copy ceiling).
// Round-6: 8x block-contiguous offsets (i .. i+7*256): one contiguous
// 32 KiB region per block per iteration, stream count stays 2048, 8 loads
// in flight per wave. n4 = 2^25, step = 2^22 -> exactly 8 iters, empty tail.

typedef int  v4i __attribute__((ext_vector_type(4)));
typedef unsigned int u32;

__device__ __forceinline__ int cz_mask(u32 b, int c2, int t2) {
    return (int)((((b >> c2) & (b >> t2)) & 1u) << 31);
}

__global__ void __launch_bounds__(256)
cz_kernel(const v4i* __restrict__ in, v4i* __restrict__ out,
          const int* __restrict__ p_ctrl, const int* __restrict__ p_tgt,
          const int* __restrict__ p_nq, int n4) {
    const int nq = *p_nq;
    const int c2 = nq - *p_ctrl - 1;
    const int t2 = nq - *p_tgt - 1;

    const int nthreads = gridDim.x * blockDim.x;   // 2^19

    if (c2 >= 2 && t2 >= 2) {
        // sign uniform across each aligned group of 4 floats
        const int step = nthreads * 8;             // 2^22
        int i = blockIdx.x * (blockDim.x * 8) + threadIdx.x;
        for (; i + 7 * blockDim.x < n4; i += step) {
            v4i v[8];
            int idx[8], m[8];
            #pragma unroll
            for (int u = 0; u < 8; ++u) {
                idx[u] = i + u * blockDim.x;       // +u*4 KiB, contiguous block footprint
                v[u] = __builtin_nontemporal_load(&in[idx[u]]);
            }
            #pragma unroll
            for (int u = 0; u < 8; ++u)
                m[u] = cz_mask((u32)idx[u] << 2, c2, t2);
            #pragma unroll
            for (int u = 0; u < 8; ++u) {
                v[u].x ^= m[u]; v[u].y ^= m[u]; v[u].z ^= m[u]; v[u].w ^= m[u];
            }
            #pragma unroll
            for (int u = 0; u < 8; ++u)
                __builtin_nontemporal_store(v[u], &out[idx[u]]);
        }
        for (; i < n4; i += nthreads) {            // tail (empty for 2^25)
            v4i v = __builtin_nontemporal_load(&in[i]);
            const int mm = cz_mask((u32)i << 2, c2, t2);
            v.x ^= mm; v.y ^= mm; v.z ^= mm; v.w ^= mm;
            __builtin_nontemporal_store(v, &out[i]);
        }
    } else {
        // general path: per-element sign (c2 or t2 inside the low 2 bits)
        for (int i = blockIdx.x * blockDim.x + threadIdx.x; i < n4; i += nthreads) {
            v4i v = __builtin_nontemporal_load(&in[i]);
            const u32 b = (u32)i << 2;
            v.x ^= cz_mask(b,     c2, t2);
            v.y ^= cz_mask(b + 1, c2, t2);
            v.z ^= cz_mask(b + 2, c2, t2);
            v.w ^= cz_mask(b + 3, c2, t2);
            __builtin_nontemporal_store(v, &out[i]);
        }
    }
}

extern "C" void kernel_launch(void* const* d_in, const int* in_sizes, int n_in,
                              void* d_out, int out_size, void* d_ws, size_t ws_size,
                              hipStream_t stream) {
    const float* state = (const float*)d_in[0];
    const int* p_ctrl  = (const int*)d_in[1];
    const int* p_tgt   = (const int*)d_in[2];
    const int* p_nq    = (const int*)d_in[3];
    float* out = (float*)d_out;

    const long long n = (long long)in_sizes[0];   // 16384 * 8192 = 2^27
    const int n4 = (int)(n >> 2);                 // 2^25

    const int block = 256;
    long long want = ((long long)n4 + block - 1) / block;
    int grid = (int)(want < 2048 ? want : 2048);  // 8 blocks/CU -> 32 waves/CU

    cz_kernel<<<grid, block, 0, stream>>>(
        (const v4i*)state, (v4i*)out, p_ctrl, p_tgt, p_nq, n4);
}

// Round 7
// 181.753 us; speedup vs baseline: 1.0261x; 1.0261x over previous
//
#include <hip/hip_runtime.h>
#include <hip/hip_bf16.h>

// CZ gate: out[i] = state[i], sign flipped iff bits c2,t2 of the flat index
// are both set (D = 2^n, so flat-index bits == column-index bits).
// Pure 1 GiB R+W streaming op; roofline = float4-copy ceiling ~6.3 TB/s.
//
// Final (r5 revert): 4x block-contiguous NT unroll = 179.5 us, 5.98 TB/s,
// 95% of the measured 6.29 TB/s copy ceiling.
// Ladder: r1 plain uint4 = 224; r2 +nontemporal = 197; r3 4x unroll at
// 8MB-separated addresses REGRESSED (247, DRAM locality); r4 2x
// block-contiguous = 190; r5 4x block-contiguous = 179.5; r6 8x = 186.5
// (REGRESSED -> 4x is the MLP saturation knee).
// Mechanism note: extra in-flight loads per wave help ONLY when the block's
// instantaneous footprint stays contiguous (i, i+256, i+512, i+768 ->
// one 16 KiB region/block/iter; stream count stays 2048).

typedef int  v4i __attribute__((ext_vector_type(4)));
typedef unsigned int u32;

__device__ __forceinline__ int cz_mask(u32 b, int c2, int t2) {
    return (int)((((b >> c2) & (b >> t2)) & 1u) << 31);
}

__global__ void __launch_bounds__(256)
cz_kernel(const v4i* __restrict__ in, v4i* __restrict__ out,
          const int* __restrict__ p_ctrl, const int* __restrict__ p_tgt,
          const int* __restrict__ p_nq, int n4) {
    const int nq = *p_nq;
    const int c2 = nq - *p_ctrl - 1;
    const int t2 = nq - *p_tgt - 1;

    const int nthreads = gridDim.x * blockDim.x;   // 2^19

    if (c2 >= 2 && t2 >= 2) {
        // sign uniform across each aligned group of 4 floats
        const int step = nthreads * 4;             // 2^21
        int i = blockIdx.x * (blockDim.x * 4) + threadIdx.x;
        for (; i + 3 * blockDim.x < n4; i += step) {
            const int i0 = i;
            const int i1 = i +     blockDim.x;     // +4 KiB
            const int i2 = i + 2 * blockDim.x;     // +8 KiB
            const int i3 = i + 3 * blockDim.x;     // +12 KiB
            v4i v0 = __builtin_nontemporal_load(&in[i0]);
            v4i v1 = __builtin_nontemporal_load(&in[i1]);
            v4i v2 = __builtin_nontemporal_load(&in[i2]);
            v4i v3 = __builtin_nontemporal_load(&in[i3]);
            const int m0 = cz_mask((u32)i0 << 2, c2, t2);
            const int m1 = cz_mask((u32)i1 << 2, c2, t2);
            const int m2 = cz_mask((u32)i2 << 2, c2, t2);
            const int m3 = cz_mask((u32)i3 << 2, c2, t2);
            v0.x ^= m0; v0.y ^= m0; v0.z ^= m0; v0.w ^= m0;
            v1.x ^= m1; v1.y ^= m1; v1.z ^= m1; v1.w ^= m1;
            v2.x ^= m2; v2.y ^= m2; v2.z ^= m2; v2.w ^= m2;
            v3.x ^= m3; v3.y ^= m3; v3.z ^= m3; v3.w ^= m3;
            __builtin_nontemporal_store(v0, &out[i0]);
            __builtin_nontemporal_store(v1, &out[i1]);
            __builtin_nontemporal_store(v2, &out[i2]);
            __builtin_nontemporal_store(v3, &out[i3]);
        }
        for (; i < n4; i += nthreads) {            // tail (empty for 2^25)
            v4i v = __builtin_nontemporal_load(&in[i]);
            const int m = cz_mask((u32)i << 2, c2, t2);
            v.x ^= m; v.y ^= m; v.z ^= m; v.w ^= m;
            __builtin_nontemporal_store(v, &out[i]);
        }
    } else {
        // general path: per-element sign (c2 or t2 inside the low 2 bits)
        for (int i = blockIdx.x * blockDim.x + threadIdx.x; i < n4; i += nthreads) {
            v4i v = __builtin_nontemporal_load(&in[i]);
            const u32 b = (u32)i << 2;
            v.x ^= cz_mask(b,     c2, t2);
            v.y ^= cz_mask(b + 1, c2, t2);
            v.z ^= cz_mask(b + 2, c2, t2);
            v.w ^= cz_mask(b + 3, c2, t2);
            __builtin_nontemporal_store(v, &out[i]);
        }
    }
}

extern "C" void kernel_launch(void* const* d_in, const int* in_sizes, int n_in,
                              void* d_out, int out_size, void* d_ws, size_t ws_size,
                              hipStream_t stream) {
    const float* state = (const float*)d_in[0];
    const int* p_ctrl  = (const int*)d_in[1];
    const int* p_tgt   = (const int*)d_in[2];
    const int* p_nq    = (const int*)d_in[3];
    float* out = (float*)d_out;

    const long long n = (long long)in_sizes[0];   // 16384 * 8192 = 2^27
    const int n4 = (int)(n >> 2);                 // 2^25

    const int block = 256;
    long long want = ((long long)n4 + block - 1) / block;
    int grid = (int)(want < 2048 ? want : 2048);  // 8 blocks/CU -> 32 waves/CU

    cz_kernel<<<grid, block, 0, stream>>>(
        (const v4i*)state, (v4i*)out, p_ctrl, p_tgt, p_nq, n4);
}